// Round 12
// baseline (118.398 us; speedup 1.0000x reference)
//
#include <hip/hip_runtime.h>
#include <hip/hip_bf16.h>
#include <math.h>

#define B_    64
#define TQ    32
#define TD    4096
#define HDIM  300
#define NB    29      // histogram bins
#define NFEAT 30      // 29 bins + exact-match feature
#define NKT   19      // ktiles of 16 (K padded 300 -> 304)
#define THREADS 256
#define DPB   128     // d-rows per block (4 waves x 2 sets x 16)
#define NSET  2
#define RDEP  6       // ring depth per set
#define QF_SLOTS (NKT * 2 * 64)        // half4 A-frag slots per batch = 2432
#define QF_F4    (QF_SLOTS / 2)        // = 1216 float4
#define QF_BYTES (QF_SLOTS * 8)        // 19456 B per batch

typedef _Float16 half4 __attribute__((ext_vector_type(4)));
typedef float    f32x4 __attribute__((ext_vector_type(4)));

// bin upper bounds: jnp.linspace(-1,1,30)[1:], ub[k] = -1 + 2(k+1)/29
__device__ __forceinline__ float ubf(int k) {
    return (float)(-1.0 + (2.0 * (double)(k + 1)) / 29.0);
}

// bin one similarity value into the per-block LDS histogram
__device__ __forceinline__ void bin_one(float sim, unsigned* s_hist, int q) {
    if (sim > 0.999f && sim < 1.001f) {
        // only exact token matches land here; true sim < 1.0 strictly -> bin 28
        atomicAdd(&s_hist[q * NFEAT + 28], 1u);
        atomicAdd(&s_hist[q * NFEAT + 29], 1u);   // exact-match feature
    } else {
        int idx = (int)((sim + 1.0f) * 14.5f);    // guess, then exact fixup
        idx = idx < 0 ? 0 : (idx > NB ? NB : idx);
        while (idx < NB && sim >= ubf(idx)) ++idx;
        while (idx > 0 && sim < ubf(idx - 1)) --idx;
        if (idx < NB) atomicAdd(&s_hist[q * NFEAT + idx], 1u);
    }
}

// ---------------- q pre-pass: gather q rows ONCE per batch -> fp16 A-frags ----
// Grid 64 x 64. Thread (row=t&31, half=t>>5): fp32 loads, exact fp32 norm
// partials (2-partial deterministic sum), fp16 A-fragment stores:
//   A lane l holds A[l%16][(l/16)*4+j]  =>  slot (kt*2 + row>>4)*64 + (row&15) + 16*g
__global__ void k_qfrag(const int* __restrict__ qsent, const float* __restrict__ emb,
                        _Float16* __restrict__ qf, float* __restrict__ invq) {
    const int b = blockIdx.x;
    const int t = threadIdx.x;
    const int row = t & 31, half = t >> 5;
    __shared__ float pn[2][TQ];
    const int tok = qsent[b * TQ + row];
    const float* p = emb + (size_t)tok * HDIM;
    _Float16* qfb = qf + (size_t)b * (QF_SLOTS * 4);
    float n = 0.f;
    for (int i = 0; i < 38; ++i) {                 // jf = half*38 + i in [0,76)
        const int jf = half * 38 + i;
        const int kg = jf * 4;
        float4 v = make_float4(0.f, 0.f, 0.f, 0.f);
        if (kg < 297) v = *(const float4*)(p + kg);    // kg<=296 covers k<=299
        n = fmaf(v.x, v.x, n); n = fmaf(v.y, v.y, n);
        n = fmaf(v.z, v.z, n); n = fmaf(v.w, v.w, n);
        half4 h = {(_Float16)v.x, (_Float16)v.y, (_Float16)v.z, (_Float16)v.w};
        const int kt = jf >> 2, g = jf & 3;
        const int slot = (kt * 2 + (row >> 4)) * 64 + (row & 15) + 16 * g;
        *(half4*)&qfb[slot * 4] = h;
    }
    pn[half][row] = n;
    __syncthreads();
    if (half == 0) {
        float s = pn[0][row] + pn[1][row];
        invq[b * TQ + row] = 1.0f / (sqrtf(s + 1e-7f) + 1e-7f);
    }
}

// ---------------- main: barrier-free register-streamed fp16-MFMA + histogram --
// Grid B_*32 blocks of 256 (4 waves); block = batch b, d-rows d0..d0+127.
// Wave w streams TWO 16-row sets (rows w*16..+15 and +64) against the same
// A-frags -> A-stage/hist-init/merge amortized 2x, two independent MLP chains
// per lane. B-fragment = 16 contiguous bytes of an emb row (lane l: row l%16,
// k-group l>>4) -> global->reg->cvt->MFMA, no LDS for d, no transpose.
// Ring prefetch depth 6 PER SET (12 loads in flight/lane). Lane reads its own
// 2 tokens straight from sent (coalesced); ring loads issue BEFORE the A-stage
// copy so gather latency hides under it; ONE barrier before the MFMA loop.
// d-norms: fp32 fmaf per k-group partial + shfl_xor(16,32) tree (determ.).
// MFMA sequence per set identical to r8-r11 -> absmax unchanged.
__global__ __launch_bounds__(THREADS) void k_main(
        const int* __restrict__ sent, const float* __restrict__ emb,
        const _Float16* __restrict__ qf, const float* __restrict__ invq,
        unsigned* __restrict__ ghist) {
    __shared__ __align__(16) _Float16 afr[QF_SLOTS * 4];   // 19456 B A-frags
    __shared__ float    s_iq[TQ];
    __shared__ unsigned s_hist[TQ * NFEAT];

    const int b    = blockIdx.x >> 5;
    const int d0   = (blockIdx.x & 31) * DPB;
    const int tid  = threadIdx.x;
    const int wid  = tid >> 6;
    const int lane = tid & 63;

    // ---- per-lane stream setup (no LDS dependency)
    const int g4   = lane >> 4;              // k-group 0..3
    const int r16  = lane & 15;
    int tok[NSET];
    const float* bp[NSET];
#pragma unroll
    for (int s = 0; s < NSET; ++s) {
        tok[s] = sent[b * TD + d0 + wid * 16 + r16 + s * 64];
        bp[s]  = emb + (size_t)tok[s] * HDIM + g4 * 4;
    }

    // guarded B load: kt=18,g4=3 would read k 300..303 (OOB of row) -> zero
    auto ldB = [&](int s, int kt) -> float4 {
        if (kt == 18 && g4 == 3) return make_float4(0.f, 0.f, 0.f, 0.f);
        return *(const float4*)(bp[s] + kt * 16);
    };

    // ---- issue ring loads FIRST (latency hides under A-stage below)
    float4 pre[NSET][RDEP];
#pragma unroll
    for (int p = 0; p < RDEP; ++p) {
#pragma unroll
        for (int s = 0; s < NSET; ++s) pre[s][p] = ldB(s, p);
    }

    // ---- hist init + A-frag stage (1216 float4, linear, L2-hot) + s_iq
    for (int i = tid; i < TQ * NFEAT; i += THREADS) s_hist[i] = 0u;
    {
        const float4* qfp = (const float4*)(qf + (size_t)b * (QF_SLOTS * 4));
        float4* afp = (float4*)afr;
        for (int i = tid; i < QF_F4; i += THREADS) afp[i] = qfp[i];
    }
    if (tid < TQ) s_iq[tid] = invq[b * TQ + tid];
    __syncthreads();

    f32x4 acc0[NSET], acc1[NSET];
    float nd[NSET];
#pragma unroll
    for (int s = 0; s < NSET; ++s) {
        acc0[s] = (f32x4){0.f, 0.f, 0.f, 0.f};
        acc1[s] = (f32x4){0.f, 0.f, 0.f, 0.f};
        nd[s] = 0.f;
    }

#pragma unroll
    for (int kt = 0; kt < NKT; ++kt) {
        half4 a0 = *(const half4*)&afr[((kt * 2 + 0) * 64 + lane) * 4];
        half4 a1 = *(const half4*)&afr[((kt * 2 + 1) * 64 + lane) * 4];
#pragma unroll
        for (int s = 0; s < NSET; ++s) {
            float4 v = pre[s][kt % RDEP];
            if (kt + RDEP < NKT) pre[s][kt % RDEP] = ldB(s, kt + RDEP);
            nd[s] = fmaf(v.x, v.x, nd[s]); nd[s] = fmaf(v.y, v.y, nd[s]);
            nd[s] = fmaf(v.z, v.z, nd[s]); nd[s] = fmaf(v.w, v.w, nd[s]);
            half4 hb = {(_Float16)v.x, (_Float16)v.y, (_Float16)v.z, (_Float16)v.w};
            acc0[s] = __builtin_amdgcn_mfma_f32_16x16x16f16(a0, hb, acc0[s], 0, 0, 0);
            acc1[s] = __builtin_amdgcn_mfma_f32_16x16x16f16(a1, hb, acc1[s], 0, 0, 0);
        }
    }

    // ---- epilogue per set: norm tree-reduce (lanes l, l^16, l^32, l^48) + bins
#pragma unroll
    for (int s = 0; s < NSET; ++s) {
        float t = nd[s];
        t += __shfl_xor(t, 16, 64);
        t += __shfl_xor(t, 32, 64);
        const float idv = 1.0f / (sqrtf(t + 1e-7f) + 1e-7f);
        if (tok[s] != 0) {         // masked doc: +1e7 -> dropped everywhere
#pragma unroll
            for (int r = 0; r < 4; ++r) {
                const int q0 = g4 * 4 + r;
                bin_one(acc0[s][r] * s_iq[q0] * idv, s_hist, q0);
                const int q1 = 16 + g4 * 4 + r;
                bin_one(acc1[s][r] * s_iq[q1] * idv, s_hist, q1);
            }
        }
    }
    __syncthreads();
    for (int i = tid; i < TQ * NFEAT; i += THREADS) {
        unsigned v = s_hist[i];
        if (v) atomicAdd(&ghist[b * TQ * NFEAT + i], v);
    }
}

// ---------------- finish: log + MLP + gate softmax ----------------
__global__ void k_finish(const unsigned* __restrict__ ghist,
                         const int* __restrict__ qsent, const float* __restrict__ idf,
                         const float* __restrict__ w1, const float* __restrict__ b1,
                         const float* __restrict__ w2, const float* __restrict__ b2,
                         const float* __restrict__ gw, const float* __restrict__ ow,
                         const float* __restrict__ ob, float* __restrict__ out) {
    int b = blockIdx.x;
    int lane = threadIdx.x;   // 64 threads, lanes 0..31 active
    float ffw = 0.f;
    float logit = -3.0e38f;
    if (lane < TQ) {
        const unsigned* h = ghist + (b * TQ + lane) * NFEAT;
        float f[NFEAT];
        for (int k = 0; k < NFEAT; ++k) f[k] = logf((float)h[k] + 1.0f);
        float s2 = b2[0];
        for (int n = 0; n < 5; ++n) {
            float s = b1[n];
            for (int k = 0; k < NFEAT; ++k) s = fmaf(f[k], w1[k * 5 + n], s);
            s2 = fmaf(tanhf(s), w2[n], s2);
        }
        ffw = tanhf(s2);
        int qt = qsent[b * TQ + lane];
        logit = idf[b * TQ + lane] * gw[0] + (qt == 0 ? -1e7f : 0.f);
    }
    float m = logit;
#pragma unroll
    for (int t = 1; t < 64; t <<= 1) m = fmaxf(m, __shfl_xor(m, t, 64));
    float e = expf(logit - m);            // inactive lanes -> exp(-inf) = 0
    float se = e, sw = e * ffw;
#pragma unroll
    for (int t = 1; t < 64; t <<= 1) {
        se += __shfl_xor(se, t, 64);
        sw += __shfl_xor(sw, t, 64);
    }
    if (lane == 0) out[b] = (sw / se) * ow[0] + ob[0];
}

extern "C" void kernel_launch(void* const* d_in, const int* in_sizes, int n_in,
                              void* d_out, int out_size, void* d_ws, size_t ws_size,
                              hipStream_t stream) {
    const int*   sent  = (const int*)d_in[0];
    const int*   qsent = (const int*)d_in[1];
    const float* idf   = (const float*)d_in[2];
    const float* emb   = (const float*)d_in[3];
    const float* w1    = (const float*)d_in[4];
    const float* b1    = (const float*)d_in[5];
    const float* w2    = (const float*)d_in[6];
    const float* b2    = (const float*)d_in[7];
    const float* gw    = (const float*)d_in[8];
    const float* ow    = (const float*)d_in[9];
    const float* ob    = (const float*)d_in[10];
    float* out = (float*)d_out;

    char* ws = (char*)d_ws;
    unsigned*  ghist = (unsigned*)ws;                       // 240 KB
    _Float16*  qfrag = (_Float16*)(ws + (256 << 10));       // 64 * 19456 B = 1.24 MB
    float*     invq  = (float*)(ws + (256 << 10) + (size_t)B_ * QF_BYTES);

    hipMemsetAsync(ghist, 0, (size_t)B_ * TQ * NFEAT * 4, stream);
    k_qfrag<<<B_, 64, 0, stream>>>(qsent, emb, qfrag, invq);
    k_main<<<B_ * (TD / DPB), THREADS, 0, stream>>>(sent, emb, qfrag, invq, ghist);
    k_finish<<<B_, 64, 0, stream>>>(ghist, qsent, idf, w1, b1, w2, b2, gw, ow, ob, out);
}

// Round 13
// 91.919 us; speedup vs baseline: 1.2881x; 1.2881x over previous
//
#include <hip/hip_runtime.h>
#include <hip/hip_bf16.h>
#include <math.h>

#define B_    64
#define TQ    32
#define TD    4096
#define HDIM  300
#define NB    29      // histogram bins
#define NFEAT 30      // 29 bins + exact-match feature
#define NKT   19      // ktiles of 16 (K padded 300 -> 304)
#define THREADS 256
#define NCH   4       // chunks per block
#define DPB   256     // d-rows per block (4 chunks x 64)
#define RDEP  6       // ring depth
#define QF_SLOTS (NKT * 2 * 64)        // half4 A-frag slots per batch = 2432
#define QF_F4    (QF_SLOTS / 2)        // = 1216 float4
#define QF_BYTES (QF_SLOTS * 8)        // 19456 B per batch

typedef _Float16 half4 __attribute__((ext_vector_type(4)));
typedef float    f32x4 __attribute__((ext_vector_type(4)));

// bin upper bounds: jnp.linspace(-1,1,30)[1:], ub[k] = -1 + 2(k+1)/29
__device__ __forceinline__ float ubf(int k) {
    return (float)(-1.0 + (2.0 * (double)(k + 1)) / 29.0);
}

// bin one similarity value into the per-block LDS histogram
__device__ __forceinline__ void bin_one(float sim, unsigned* s_hist, int q) {
    if (sim > 0.999f && sim < 1.001f) {
        // only exact token matches land here; true sim < 1.0 strictly -> bin 28
        atomicAdd(&s_hist[q * NFEAT + 28], 1u);
        atomicAdd(&s_hist[q * NFEAT + 29], 1u);   // exact-match feature
    } else {
        int idx = (int)((sim + 1.0f) * 14.5f);    // guess, then exact fixup
        idx = idx < 0 ? 0 : (idx > NB ? NB : idx);
        while (idx < NB && sim >= ubf(idx)) ++idx;
        while (idx > 0 && sim < ubf(idx - 1)) --idx;
        if (idx < NB) atomicAdd(&s_hist[q * NFEAT + idx], 1u);
    }
}

// ---------------- q pre-pass: gather q rows ONCE per batch -> fp16 A-frags ----
// Grid 64 x 256. Thread (row=t&31, seg=t>>5 in 0..7) stages ~1/8 of the k-range
// of q-row `row`: fp32 loads, fp32 norm partial (8-partial deterministic sum),
// fp16 A-fragment stores: A lane l holds A[l%16][(l/16)*4+j] =>
//   slot (kt*2 + row>>4)*64 + (row&15) + 16*g
__global__ void k_qfrag(const int* __restrict__ qsent, const float* __restrict__ emb,
                        _Float16* __restrict__ qf, float* __restrict__ invq) {
    const int b = blockIdx.x;
    const int t = threadIdx.x;
    const int row = t & 31, seg = t >> 5;
    __shared__ float pn[8][TQ];
    const int tok = qsent[b * TQ + row];
    const float* p = emb + (size_t)tok * HDIM;
    _Float16* qfb = qf + (size_t)b * (QF_SLOTS * 4);
    float n = 0.f;
#pragma unroll
    for (int i = 0; i < 10; ++i) {                 // jf = seg*10 + i, valid < 76
        const int jf = seg * 10 + i;
        if (jf < 76) {
            const int kg = jf * 4;
            float4 v = make_float4(0.f, 0.f, 0.f, 0.f);
            if (kg < 297) v = *(const float4*)(p + kg);    // kg<=296 covers k<=299
            n = fmaf(v.x, v.x, n); n = fmaf(v.y, v.y, n);
            n = fmaf(v.z, v.z, n); n = fmaf(v.w, v.w, n);
            half4 h = {(_Float16)v.x, (_Float16)v.y, (_Float16)v.z, (_Float16)v.w};
            const int kt = jf >> 2, g = jf & 3;
            const int slot = (kt * 2 + (row >> 4)) * 64 + (row & 15) + 16 * g;
            *(half4*)&qfb[slot * 4] = h;
        }
    }
    pn[seg][row] = n;
    __syncthreads();
    if (t < TQ) {
        float s = ((pn[0][t] + pn[1][t]) + (pn[2][t] + pn[3][t]))
                + ((pn[4][t] + pn[5][t]) + (pn[6][t] + pn[7][t]));
        invq[b * TQ + t] = 1.0f / (sqrtf(s + 1e-7f) + 1e-7f);
    }
}

// ---------------- main: persistent-chunk register-streamed fp16-MFMA ----------
// Grid B_*16 blocks of 256 (4 waves); block = batch b, d-rows d0..d0+255 in
// 4 chunks of 64 (wave w, chunk ch: rows ch*64 + w*16 .. +15). A-frags staged
// ONCE per block (19.5 KB LDS); hist merged once -> constants amortized 4x vs
// r11. B-fragment = 16 contiguous bytes of an emb row (lane l: row l%16,
// k-group l>>4) -> global->reg->cvt->MFMA, no LDS for d.
// CONTINUOUS ring: global step g = ch*19+kt, slot g%RDEP, refill g+RDEP --
// both loops fully unrolled so slots are compile-time (regs, rule #20) and
// next chunk's loads issue under the current chunk's MFMA tail: gather startup
// latency paid once per block, not per chunk. acc/nd reset per chunk (8 VGPR
// reused); per-row cvt/MFMA/norm order identical to r11 -> absmax unchanged.
__global__ __launch_bounds__(THREADS) void k_main(
        const int* __restrict__ sent, const float* __restrict__ emb,
        const _Float16* __restrict__ qf, const float* __restrict__ invq,
        unsigned* __restrict__ ghist) {
    __shared__ __align__(16) _Float16 afr[QF_SLOTS * 4];   // 19456 B A-frags
    __shared__ float    s_iq[TQ];
    __shared__ unsigned s_hist[TQ * NFEAT];

    const int b    = blockIdx.x >> 4;
    const int d0   = (blockIdx.x & 15) * DPB;
    const int tid  = threadIdx.x;
    const int wid  = tid >> 6;
    const int lane = tid & 63;

    const int g4   = lane >> 4;              // k-group 0..3
    const int r16  = lane & 15;

    int tok[NCH];
    const float* bp[NCH];
#pragma unroll
    for (int ch = 0; ch < NCH; ++ch) {
        tok[ch] = sent[b * TD + d0 + ch * 64 + wid * 16 + r16];
        bp[ch]  = emb + (size_t)tok[ch] * HDIM + g4 * 4;
    }

    // guarded B load by global step g (compile-time ch/kt after unroll);
    // kt=18,g4=3 would read k 300..303 (OOB of row) -> zero
    auto ldBg = [&](int g) -> float4 {
        const int ch = g / NKT, kt = g - ch * NKT;
        if (kt == 18 && g4 == 3) return make_float4(0.f, 0.f, 0.f, 0.f);
        return *(const float4*)(bp[ch] + kt * 16);
    };

    // ---- issue first ring loads (latency hides under A-stage below)
    float4 pre[RDEP];
#pragma unroll
    for (int p = 0; p < RDEP; ++p) pre[p] = ldBg(p);

    // ---- hist init + A-frag stage (1216 float4, linear, L2-hot) + s_iq
    for (int i = tid; i < TQ * NFEAT; i += THREADS) s_hist[i] = 0u;
    {
        const float4* qfp = (const float4*)(qf + (size_t)b * (QF_SLOTS * 4));
        float4* afp = (float4*)afr;
        for (int i = tid; i < QF_F4; i += THREADS) afp[i] = qfp[i];
    }
    if (tid < TQ) s_iq[tid] = invq[b * TQ + tid];
    __syncthreads();

#pragma unroll
    for (int ch = 0; ch < NCH; ++ch) {
        f32x4 acc0 = {0.f, 0.f, 0.f, 0.f};
        f32x4 acc1 = {0.f, 0.f, 0.f, 0.f};
        float nd = 0.f;
#pragma unroll
        for (int kt = 0; kt < NKT; ++kt) {
            const int g = ch * NKT + kt;
            float4 v = pre[g % RDEP];
            if (g + RDEP < NCH * NKT) pre[g % RDEP] = ldBg(g + RDEP);
            nd = fmaf(v.x, v.x, nd); nd = fmaf(v.y, v.y, nd);
            nd = fmaf(v.z, v.z, nd); nd = fmaf(v.w, v.w, nd);
            half4 hb = {(_Float16)v.x, (_Float16)v.y, (_Float16)v.z, (_Float16)v.w};
            half4 a0 = *(const half4*)&afr[((kt * 2 + 0) * 64 + lane) * 4];
            half4 a1 = *(const half4*)&afr[((kt * 2 + 1) * 64 + lane) * 4];
            acc0 = __builtin_amdgcn_mfma_f32_16x16x16f16(a0, hb, acc0, 0, 0, 0);
            acc1 = __builtin_amdgcn_mfma_f32_16x16x16f16(a1, hb, acc1, 0, 0, 0);
        }
        // ---- per-chunk epilogue: norm tree (lanes l^16, l^32) + bins
        float t = nd;
        t += __shfl_xor(t, 16, 64);
        t += __shfl_xor(t, 32, 64);
        const float idv = 1.0f / (sqrtf(t + 1e-7f) + 1e-7f);
        if (tok[ch] != 0) {        // masked doc: +1e7 -> dropped everywhere
#pragma unroll
            for (int r = 0; r < 4; ++r) {
                const int q0 = g4 * 4 + r;
                bin_one(acc0[r] * s_iq[q0] * idv, s_hist, q0);
                const int q1 = 16 + g4 * 4 + r;
                bin_one(acc1[r] * s_iq[q1] * idv, s_hist, q1);
            }
        }
    }
    __syncthreads();
    for (int i = tid; i < TQ * NFEAT; i += THREADS) {
        unsigned v = s_hist[i];
        if (v) atomicAdd(&ghist[b * TQ * NFEAT + i], v);
    }
}

// ---------------- finish: log + MLP + gate softmax ----------------
__global__ void k_finish(const unsigned* __restrict__ ghist,
                         const int* __restrict__ qsent, const float* __restrict__ idf,
                         const float* __restrict__ w1, const float* __restrict__ b1,
                         const float* __restrict__ w2, const float* __restrict__ b2,
                         const float* __restrict__ gw, const float* __restrict__ ow,
                         const float* __restrict__ ob, float* __restrict__ out) {
    int b = blockIdx.x;
    int lane = threadIdx.x;   // 64 threads, lanes 0..31 active
    float ffw = 0.f;
    float logit = -3.0e38f;
    if (lane < TQ) {
        const unsigned* h = ghist + (b * TQ + lane) * NFEAT;
        float f[NFEAT];
        for (int k = 0; k < NFEAT; ++k) f[k] = logf((float)h[k] + 1.0f);
        float s2 = b2[0];
        for (int n = 0; n < 5; ++n) {
            float s = b1[n];
            for (int k = 0; k < NFEAT; ++k) s = fmaf(f[k], w1[k * 5 + n], s);
            s2 = fmaf(tanhf(s), w2[n], s2);
        }
        ffw = tanhf(s2);
        int qt = qsent[b * TQ + lane];
        logit = idf[b * TQ + lane] * gw[0] + (qt == 0 ? -1e7f : 0.f);
    }
    float m = logit;
#pragma unroll
    for (int t = 1; t < 64; t <<= 1) m = fmaxf(m, __shfl_xor(m, t, 64));
    float e = expf(logit - m);            // inactive lanes -> exp(-inf) = 0
    float se = e, sw = e * ffw;
#pragma unroll
    for (int t = 1; t < 64; t <<= 1) {
        se += __shfl_xor(se, t, 64);
        sw += __shfl_xor(sw, t, 64);
    }
    if (lane == 0) out[b] = (sw / se) * ow[0] + ob[0];
}

extern "C" void kernel_launch(void* const* d_in, const int* in_sizes, int n_in,
                              void* d_out, int out_size, void* d_ws, size_t ws_size,
                              hipStream_t stream) {
    const int*   sent  = (const int*)d_in[0];
    const int*   qsent = (const int*)d_in[1];
    const float* idf   = (const float*)d_in[2];
    const float* emb   = (const float*)d_in[3];
    const float* w1    = (const float*)d_in[4];
    const float* b1    = (const float*)d_in[5];
    const float* w2    = (const float*)d_in[6];
    const float* b2    = (const float*)d_in[7];
    const float* gw    = (const float*)d_in[8];
    const float* ow    = (const float*)d_in[9];
    const float* ob    = (const float*)d_in[10];
    float* out = (float*)d_out;

    char* ws = (char*)d_ws;
    unsigned*  ghist = (unsigned*)ws;                       // 240 KB
    _Float16*  qfrag = (_Float16*)(ws + (256 << 10));       // 64 * 19456 B = 1.24 MB
    float*     invq  = (float*)(ws + (256 << 10) + (size_t)B_ * QF_BYTES);

    hipMemsetAsync(ghist, 0, (size_t)B_ * TQ * NFEAT * 4, stream);
    k_qfrag<<<B_, 256, 0, stream>>>(qsent, emb, qfrag, invq);
    k_main<<<B_ * (TD / DPB), THREADS, 0, stream>>>(sent, emb, qfrag, invq, ghist);
    k_finish<<<B_, 64, 0, stream>>>(ghist, qsent, idf, w1, b1, w2, b2, gw, ow, ob, out);
}

// Round 14
// 82.893 us; speedup vs baseline: 1.4283x; 1.1089x over previous
//
#include <hip/hip_runtime.h>
#include <hip/hip_bf16.h>
#include <math.h>

#define B_    64
#define TQ    32
#define TD    4096
#define HDIM  300
#define NB    29      // histogram bins
#define NFEAT 30      // 29 bins + exact-match feature
#define NKT   19      // ktiles of 16 (K padded 300 -> 304)
#define THREADS 256
#define NCH   2       // chunks per block
#define DPB   128     // d-rows per block (2 chunks x 64)
#define RDEP  8       // ring depth
#define QF_SLOTS (NKT * 2 * 64)        // half4 A-frag slots per batch = 2432
#define QF_F4    (QF_SLOTS / 2)        // = 1216 float4
#define QF_BYTES (QF_SLOTS * 8)        // 19456 B per batch

typedef _Float16 half4 __attribute__((ext_vector_type(4)));
typedef float    f32x4 __attribute__((ext_vector_type(4)));

// bin upper bounds: jnp.linspace(-1,1,30)[1:], ub[k] = -1 + 2(k+1)/29
__device__ __forceinline__ float ubf(int k) {
    return (float)(-1.0 + (2.0 * (double)(k + 1)) / 29.0);
}

// bin one similarity value into the per-block LDS histogram
__device__ __forceinline__ void bin_one(float sim, unsigned* s_hist, int q) {
    if (sim > 0.999f && sim < 1.001f) {
        // only exact token matches land here; true sim < 1.0 strictly -> bin 28
        atomicAdd(&s_hist[q * NFEAT + 28], 1u);
        atomicAdd(&s_hist[q * NFEAT + 29], 1u);   // exact-match feature
    } else {
        int idx = (int)((sim + 1.0f) * 14.5f);    // guess, then exact fixup
        idx = idx < 0 ? 0 : (idx > NB ? NB : idx);
        while (idx < NB && sim >= ubf(idx)) ++idx;
        while (idx > 0 && sim < ubf(idx - 1)) --idx;
        if (idx < NB) atomicAdd(&s_hist[q * NFEAT + idx], 1u);
    }
}

// ---------------- q pre-pass: gather q rows ONCE per batch -> fp16 A-frags ----
// Grid 64 x 256. Thread (row=t&31, seg=t>>5 in 0..7) stages ~1/8 of the k-range
// of q-row `row`: fp32 loads, fp32 norm partial (8-partial deterministic sum),
// fp16 A-fragment stores: A lane l holds A[l%16][(l/16)*4+j] =>
//   slot (kt*2 + row>>4)*64 + (row&15) + 16*g
// Also zeroes this batch's ghist slice (replaces the hipMemsetAsync launch).
__global__ void k_qfrag(const int* __restrict__ qsent, const float* __restrict__ emb,
                        _Float16* __restrict__ qf, float* __restrict__ invq,
                        unsigned* __restrict__ ghist) {
    const int b = blockIdx.x;
    const int t = threadIdx.x;
    const int row = t & 31, seg = t >> 5;
    __shared__ float pn[8][TQ];
    for (int i = t; i < TQ * NFEAT; i += 256) ghist[b * TQ * NFEAT + i] = 0u;
    const int tok = qsent[b * TQ + row];
    const float* p = emb + (size_t)tok * HDIM;
    _Float16* qfb = qf + (size_t)b * (QF_SLOTS * 4);
    float n = 0.f;
#pragma unroll
    for (int i = 0; i < 10; ++i) {                 // jf = seg*10 + i, valid < 76
        const int jf = seg * 10 + i;
        if (jf < 76) {
            const int kg = jf * 4;
            float4 v = make_float4(0.f, 0.f, 0.f, 0.f);
            if (kg < 297) v = *(const float4*)(p + kg);    // kg<=296 covers k<=299
            n = fmaf(v.x, v.x, n); n = fmaf(v.y, v.y, n);
            n = fmaf(v.z, v.z, n); n = fmaf(v.w, v.w, n);
            half4 h = {(_Float16)v.x, (_Float16)v.y, (_Float16)v.z, (_Float16)v.w};
            const int kt = jf >> 2, g = jf & 3;
            const int slot = (kt * 2 + (row >> 4)) * 64 + (row & 15) + 16 * g;
            *(half4*)&qfb[slot * 4] = h;
        }
    }
    pn[seg][row] = n;
    __syncthreads();
    if (t < TQ) {
        float s = ((pn[0][t] + pn[1][t]) + (pn[2][t] + pn[3][t]))
                + ((pn[4][t] + pn[5][t]) + (pn[6][t] + pn[7][t]));
        invq[b * TQ + t] = 1.0f / (sqrtf(s + 1e-7f) + 1e-7f);
    }
}

// ---------------- main: persistent-chunk register-streamed fp16-MFMA ----------
// Grid B_*32 blocks of 256 (4 waves); block = batch b, d-rows d0..d0+127 in
// 2 chunks of 64 (wave w, chunk ch: rows ch*64 + w*16 .. +15). A-frags staged
// once per block (19.5 KB LDS -> 6 blocks/CU resident; grid 2048 = 8 blocks/CU
// issued -> turnover overlap, the r13 grid gave exactly 4 with zero overlap).
// B-fragment = 16 contiguous bytes of an emb row (lane l: row l%16, k-group
// l>>4) -> global->reg->cvt->MFMA, no LDS for d.
// CONTINUOUS ring: global step g = ch*19+kt, slot g%RDEP (depth 8), refill
// g+RDEP -- fully unrolled so slots stay in registers (rule #20); next chunk's
// loads issue under the current chunk's MFMA tail. acc/nd reset per chunk;
// per-row cvt/MFMA/norm order identical to r11-r13 -> absmax unchanged.
__global__ __launch_bounds__(THREADS) void k_main(
        const int* __restrict__ sent, const float* __restrict__ emb,
        const _Float16* __restrict__ qf, const float* __restrict__ invq,
        unsigned* __restrict__ ghist) {
    __shared__ __align__(16) _Float16 afr[QF_SLOTS * 4];   // 19456 B A-frags
    __shared__ float    s_iq[TQ];
    __shared__ unsigned s_hist[TQ * NFEAT];

    const int b    = blockIdx.x >> 5;
    const int d0   = (blockIdx.x & 31) * DPB;
    const int tid  = threadIdx.x;
    const int wid  = tid >> 6;
    const int lane = tid & 63;

    const int g4   = lane >> 4;              // k-group 0..3
    const int r16  = lane & 15;

    int tok[NCH];
    const float* bp[NCH];
#pragma unroll
    for (int ch = 0; ch < NCH; ++ch) {
        tok[ch] = sent[b * TD + d0 + ch * 64 + wid * 16 + r16];
        bp[ch]  = emb + (size_t)tok[ch] * HDIM + g4 * 4;
    }

    // guarded B load by global step g (compile-time ch/kt after unroll);
    // kt=18,g4=3 would read k 300..303 (OOB of row) -> zero
    auto ldBg = [&](int g) -> float4 {
        const int ch = g / NKT, kt = g - ch * NKT;
        if (kt == 18 && g4 == 3) return make_float4(0.f, 0.f, 0.f, 0.f);
        return *(const float4*)(bp[ch] + kt * 16);
    };

    // ---- issue first ring loads (latency hides under A-stage below)
    float4 pre[RDEP];
#pragma unroll
    for (int p = 0; p < RDEP; ++p) pre[p] = ldBg(p);

    // ---- hist init + A-frag stage (1216 float4, linear, L2-hot) + s_iq
    for (int i = tid; i < TQ * NFEAT; i += THREADS) s_hist[i] = 0u;
    {
        const float4* qfp = (const float4*)(qf + (size_t)b * (QF_SLOTS * 4));
        float4* afp = (float4*)afr;
        for (int i = tid; i < QF_F4; i += THREADS) afp[i] = qfp[i];
    }
    if (tid < TQ) s_iq[tid] = invq[b * TQ + tid];
    __syncthreads();

#pragma unroll
    for (int ch = 0; ch < NCH; ++ch) {
        f32x4 acc0 = {0.f, 0.f, 0.f, 0.f};
        f32x4 acc1 = {0.f, 0.f, 0.f, 0.f};
        float nd = 0.f;
#pragma unroll
        for (int kt = 0; kt < NKT; ++kt) {
            const int g = ch * NKT + kt;
            float4 v = pre[g % RDEP];
            if (g + RDEP < NCH * NKT) pre[g % RDEP] = ldBg(g + RDEP);
            nd = fmaf(v.x, v.x, nd); nd = fmaf(v.y, v.y, nd);
            nd = fmaf(v.z, v.z, nd); nd = fmaf(v.w, v.w, nd);
            half4 hb = {(_Float16)v.x, (_Float16)v.y, (_Float16)v.z, (_Float16)v.w};
            half4 a0 = *(const half4*)&afr[((kt * 2 + 0) * 64 + lane) * 4];
            half4 a1 = *(const half4*)&afr[((kt * 2 + 1) * 64 + lane) * 4];
            acc0 = __builtin_amdgcn_mfma_f32_16x16x16f16(a0, hb, acc0, 0, 0, 0);
            acc1 = __builtin_amdgcn_mfma_f32_16x16x16f16(a1, hb, acc1, 0, 0, 0);
        }
        // ---- per-chunk epilogue: norm tree (lanes l^16, l^32) + bins
        float t = nd;
        t += __shfl_xor(t, 16, 64);
        t += __shfl_xor(t, 32, 64);
        const float idv = 1.0f / (sqrtf(t + 1e-7f) + 1e-7f);
        if (tok[ch] != 0) {        // masked doc: +1e7 -> dropped everywhere
#pragma unroll
            for (int r = 0; r < 4; ++r) {
                const int q0 = g4 * 4 + r;
                bin_one(acc0[r] * s_iq[q0] * idv, s_hist, q0);
                const int q1 = 16 + g4 * 4 + r;
                bin_one(acc1[r] * s_iq[q1] * idv, s_hist, q1);
            }
        }
    }
    __syncthreads();
    for (int i = tid; i < TQ * NFEAT; i += THREADS) {
        unsigned v = s_hist[i];
        if (v) atomicAdd(&ghist[b * TQ * NFEAT + i], v);
    }
}

// ---------------- finish: log + MLP + gate softmax ----------------
__global__ void k_finish(const unsigned* __restrict__ ghist,
                         const int* __restrict__ qsent, const float* __restrict__ idf,
                         const float* __restrict__ w1, const float* __restrict__ b1,
                         const float* __restrict__ w2, const float* __restrict__ b2,
                         const float* __restrict__ gw, const float* __restrict__ ow,
                         const float* __restrict__ ob, float* __restrict__ out) {
    int b = blockIdx.x;
    int lane = threadIdx.x;   // 64 threads, lanes 0..31 active
    float ffw = 0.f;
    float logit = -3.0e38f;
    if (lane < TQ) {
        const unsigned* h = ghist + (b * TQ + lane) * NFEAT;
        float f[NFEAT];
        for (int k = 0; k < NFEAT; ++k) f[k] = logf((float)h[k] + 1.0f);
        float s2 = b2[0];
        for (int n = 0; n < 5; ++n) {
            float s = b1[n];
            for (int k = 0; k < NFEAT; ++k) s = fmaf(f[k], w1[k * 5 + n], s);
            s2 = fmaf(tanhf(s), w2[n], s2);
        }
        ffw = tanhf(s2);
        int qt = qsent[b * TQ + lane];
        logit = idf[b * TQ + lane] * gw[0] + (qt == 0 ? -1e7f : 0.f);
    }
    float m = logit;
#pragma unroll
    for (int t = 1; t < 64; t <<= 1) m = fmaxf(m, __shfl_xor(m, t, 64));
    float e = expf(logit - m);            // inactive lanes -> exp(-inf) = 0
    float se = e, sw = e * ffw;
#pragma unroll
    for (int t = 1; t < 64; t <<= 1) {
        se += __shfl_xor(se, t, 64);
        sw += __shfl_xor(sw, t, 64);
    }
    if (lane == 0) out[b] = (sw / se) * ow[0] + ob[0];
}

extern "C" void kernel_launch(void* const* d_in, const int* in_sizes, int n_in,
                              void* d_out, int out_size, void* d_ws, size_t ws_size,
                              hipStream_t stream) {
    const int*   sent  = (const int*)d_in[0];
    const int*   qsent = (const int*)d_in[1];
    const float* idf   = (const float*)d_in[2];
    const float* emb   = (const float*)d_in[3];
    const float* w1    = (const float*)d_in[4];
    const float* b1    = (const float*)d_in[5];
    const float* w2    = (const float*)d_in[6];
    const float* b2    = (const float*)d_in[7];
    const float* gw    = (const float*)d_in[8];
    const float* ow    = (const float*)d_in[9];
    const float* ob    = (const float*)d_in[10];
    float* out = (float*)d_out;

    char* ws = (char*)d_ws;
    unsigned*  ghist = (unsigned*)ws;                       // 240 KB
    _Float16*  qfrag = (_Float16*)(ws + (256 << 10));       // 64 * 19456 B = 1.24 MB
    float*     invq  = (float*)(ws + (256 << 10) + (size_t)B_ * QF_BYTES);

    k_qfrag<<<B_, 256, 0, stream>>>(qsent, emb, qfrag, invq, ghist);
    k_main<<<B_ * (TD / DPB), THREADS, 0, stream>>>(sent, emb, qfrag, invq, ghist);
    k_finish<<<B_, 64, 0, stream>>>(ghist, qsent, idf, w1, b1, w2, b2, gw, ow, ob, out);
}

// Round 15
// 80.761 us; speedup vs baseline: 1.4660x; 1.0264x over previous
//
#include <hip/hip_runtime.h>
#include <hip/hip_bf16.h>
#include <math.h>

#define B_    64
#define TQ    32
#define TD    4096
#define HDIM  300
#define NB    29      // histogram bins
#define NFEAT 30      // 29 bins + exact-match feature
#define NKT   19      // ktiles of 16 (K padded 300 -> 304)
#define THREADS 256
#define NCH   2       // chunks per block
#define DPB   128     // d-rows per block (2 chunks x 64)
#define RDEP  8       // ring depth
#define NBUCK 1024    // token buckets (tok>>7 < 782)
#define QF_SLOTS (NKT * 2 * 64)        // half4 A-frag slots per batch = 2432
#define QF_F4    (QF_SLOTS / 2)        // = 1216 float4
#define QF_BYTES (QF_SLOTS * 8)        // 19456 B per batch

typedef _Float16 half4 __attribute__((ext_vector_type(4)));
typedef float    f32x4 __attribute__((ext_vector_type(4)));

// bin upper bounds: jnp.linspace(-1,1,30)[1:], ub[k] = -1 + 2(k+1)/29
__device__ __forceinline__ float ubf(int k) {
    return (float)(-1.0 + (2.0 * (double)(k + 1)) / 29.0);
}

// bin one similarity value into the per-block LDS histogram
__device__ __forceinline__ void bin_one(float sim, unsigned* s_hist, int q) {
    if (sim > 0.999f && sim < 1.001f) {
        // only exact token matches land here; true sim < 1.0 strictly -> bin 28
        atomicAdd(&s_hist[q * NFEAT + 28], 1u);
        atomicAdd(&s_hist[q * NFEAT + 29], 1u);   // exact-match feature
    } else {
        int idx = (int)((sim + 1.0f) * 14.5f);    // guess, then exact fixup
        idx = idx < 0 ? 0 : (idx > NB ? NB : idx);
        while (idx < NB && sim >= ubf(idx)) ++idx;
        while (idx > 0 && sim < ubf(idx - 1)) --idx;
        if (idx < NB) atomicAdd(&s_hist[q * NFEAT + idx], 1u);
    }
}

// ---------------- d-token bucket sort (per batch) -----------------------------
// The histogram/norms/mask are PERMUTATION-INVARIANT over d (per-row values
// depend only on the token; ghist is a sum of integer atomic increments), so
// d-rows may be processed in any order. Bucket-sort tokens ascending (1024
// buckets of ~4 ids, ~98 tokens each): duplicates become cache-adjacent and
// each k_main block's 128 rows map to a ~contiguous emb range -> random HBM
// gather becomes an ascending sweep. Within-bucket scatter order via atomics
// is run-to-run nondeterministic, but d_out is bit-identical (sum-invariant).
__global__ void k_sort(const int* __restrict__ sent, int* __restrict__ sorted) {
    const int b = blockIdx.x;
    const int t = threadIdx.x;          // 256
    const int lane = t & 63, wv = t >> 6;
    __shared__ unsigned cnt[NBUCK];
    __shared__ unsigned wtot[4];
    for (int i = t; i < NBUCK; i += 256) cnt[i] = 0u;
    __syncthreads();
    int tk[16];
#pragma unroll
    for (int j = 0; j < 16; ++j) tk[j] = sent[b * TD + j * 256 + t];
#pragma unroll
    for (int j = 0; j < 16; ++j) atomicAdd(&cnt[(unsigned)tk[j] >> 7], 1u);
    __syncthreads();
    // exclusive prefix over 1024 buckets; thread owns buckets 4t..4t+3
    unsigned c0 = cnt[t * 4], c1 = cnt[t * 4 + 1], c2 = cnt[t * 4 + 2], c3 = cnt[t * 4 + 3];
    unsigned s = c0 + c1 + c2 + c3;
    unsigned v = s;
#pragma unroll
    for (int d = 1; d < 64; d <<= 1) {
        unsigned n = __shfl_up(v, d, 64);
        if (lane >= d) v += n;
    }
    if (lane == 63) wtot[wv] = v;
    __syncthreads();
    unsigned wbase = 0;
    for (int w = 0; w < wv; ++w) wbase += wtot[w];
    const unsigned base = wbase + v - s;           // exclusive prefix for 4t
    __syncthreads();                               // all reads of cnt done
    cnt[t * 4]     = base;
    cnt[t * 4 + 1] = base + c0;
    cnt[t * 4 + 2] = base + c0 + c1;
    cnt[t * 4 + 3] = base + c0 + c1 + c2;
    __syncthreads();
#pragma unroll
    for (int j = 0; j < 16; ++j) {
        unsigned pos = atomicAdd(&cnt[(unsigned)tk[j] >> 7], 1u);
        sorted[b * TD + pos] = tk[j];
    }
}

// ---------------- q pre-pass: gather q rows ONCE per batch -> fp16 A-frags ----
// Grid 64 x 256. Thread (row=t&31, seg=t>>5 in 0..7) stages ~1/8 of the k-range
// of q-row `row`: fp32 loads, fp32 norm partial (8-partial deterministic sum),
// fp16 A-fragment stores: A lane l holds A[l%16][(l/16)*4+j] =>
//   slot (kt*2 + row>>4)*64 + (row&15) + 16*g
// Also zeroes this batch's ghist slice (replaces the hipMemsetAsync launch).
__global__ void k_qfrag(const int* __restrict__ qsent, const float* __restrict__ emb,
                        _Float16* __restrict__ qf, float* __restrict__ invq,
                        unsigned* __restrict__ ghist) {
    const int b = blockIdx.x;
    const int t = threadIdx.x;
    const int row = t & 31, seg = t >> 5;
    __shared__ float pn[8][TQ];
    for (int i = t; i < TQ * NFEAT; i += 256) ghist[b * TQ * NFEAT + i] = 0u;
    const int tok = qsent[b * TQ + row];
    const float* p = emb + (size_t)tok * HDIM;
    _Float16* qfb = qf + (size_t)b * (QF_SLOTS * 4);
    float n = 0.f;
#pragma unroll
    for (int i = 0; i < 10; ++i) {                 // jf = seg*10 + i, valid < 76
        const int jf = seg * 10 + i;
        if (jf < 76) {
            const int kg = jf * 4;
            float4 v = make_float4(0.f, 0.f, 0.f, 0.f);
            if (kg < 297) v = *(const float4*)(p + kg);    // kg<=296 covers k<=299
            n = fmaf(v.x, v.x, n); n = fmaf(v.y, v.y, n);
            n = fmaf(v.z, v.z, n); n = fmaf(v.w, v.w, n);
            half4 h = {(_Float16)v.x, (_Float16)v.y, (_Float16)v.z, (_Float16)v.w};
            const int kt = jf >> 2, g = jf & 3;
            const int slot = (kt * 2 + (row >> 4)) * 64 + (row & 15) + 16 * g;
            *(half4*)&qfb[slot * 4] = h;
        }
    }
    pn[seg][row] = n;
    __syncthreads();
    if (t < TQ) {
        float s = ((pn[0][t] + pn[1][t]) + (pn[2][t] + pn[3][t]))
                + ((pn[4][t] + pn[5][t]) + (pn[6][t] + pn[7][t]));
        invq[b * TQ + t] = 1.0f / (sqrtf(s + 1e-7f) + 1e-7f);
    }
}

// ---------------- main: persistent-chunk register-streamed fp16-MFMA ----------
// Identical to r14 except d-rows come from the bucket-sorted token array.
// Grid B_*32 blocks of 256 (4 waves); block = batch b, sorted rows d0..d0+127
// in 2 chunks of 64. A-frags staged once per block (19.5 KB LDS). B-fragment =
// 16 contiguous bytes of an emb row (lane l: row l%16, k-group l>>4) ->
// global->reg->cvt->MFMA, no LDS for d. Continuous register ring (depth 8,
// fully unrolled -> slots stay in registers). Per-row cvt/MFMA/norm order
// identical to r11-r14 -> ghist and d_out bit-identical.
__global__ __launch_bounds__(THREADS) void k_main(
        const int* __restrict__ sorted, const float* __restrict__ emb,
        const _Float16* __restrict__ qf, const float* __restrict__ invq,
        unsigned* __restrict__ ghist) {
    __shared__ __align__(16) _Float16 afr[QF_SLOTS * 4];   // 19456 B A-frags
    __shared__ float    s_iq[TQ];
    __shared__ unsigned s_hist[TQ * NFEAT];

    const int b    = blockIdx.x >> 5;
    const int d0   = (blockIdx.x & 31) * DPB;
    const int tid  = threadIdx.x;
    const int wid  = tid >> 6;
    const int lane = tid & 63;

    const int g4   = lane >> 4;              // k-group 0..3
    const int r16  = lane & 15;

    int tok[NCH];
    const float* bp[NCH];
#pragma unroll
    for (int ch = 0; ch < NCH; ++ch) {
        tok[ch] = sorted[b * TD + d0 + ch * 64 + wid * 16 + r16];
        bp[ch]  = emb + (size_t)tok[ch] * HDIM + g4 * 4;
    }

    // guarded B load by global step g (compile-time ch/kt after unroll);
    // kt=18,g4=3 would read k 300..303 (OOB of row) -> zero
    auto ldBg = [&](int g) -> float4 {
        const int ch = g / NKT, kt = g - ch * NKT;
        if (kt == 18 && g4 == 3) return make_float4(0.f, 0.f, 0.f, 0.f);
        return *(const float4*)(bp[ch] + kt * 16);
    };

    // ---- issue first ring loads (latency hides under A-stage below)
    float4 pre[RDEP];
#pragma unroll
    for (int p = 0; p < RDEP; ++p) pre[p] = ldBg(p);

    // ---- hist init + A-frag stage (1216 float4, linear, L2-hot) + s_iq
    for (int i = tid; i < TQ * NFEAT; i += THREADS) s_hist[i] = 0u;
    {
        const float4* qfp = (const float4*)(qf + (size_t)b * (QF_SLOTS * 4));
        float4* afp = (float4*)afr;
        for (int i = tid; i < QF_F4; i += THREADS) afp[i] = qfp[i];
    }
    if (tid < TQ) s_iq[tid] = invq[b * TQ + tid];
    __syncthreads();

#pragma unroll
    for (int ch = 0; ch < NCH; ++ch) {
        f32x4 acc0 = {0.f, 0.f, 0.f, 0.f};
        f32x4 acc1 = {0.f, 0.f, 0.f, 0.f};
        float nd = 0.f;
#pragma unroll
        for (int kt = 0; kt < NKT; ++kt) {
            const int g = ch * NKT + kt;
            float4 v = pre[g % RDEP];
            if (g + RDEP < NCH * NKT) pre[g % RDEP] = ldBg(g + RDEP);
            nd = fmaf(v.x, v.x, nd); nd = fmaf(v.y, v.y, nd);
            nd = fmaf(v.z, v.z, nd); nd = fmaf(v.w, v.w, nd);
            half4 hb = {(_Float16)v.x, (_Float16)v.y, (_Float16)v.z, (_Float16)v.w};
            half4 a0 = *(const half4*)&afr[((kt * 2 + 0) * 64 + lane) * 4];
            half4 a1 = *(const half4*)&afr[((kt * 2 + 1) * 64 + lane) * 4];
            acc0 = __builtin_amdgcn_mfma_f32_16x16x16f16(a0, hb, acc0, 0, 0, 0);
            acc1 = __builtin_amdgcn_mfma_f32_16x16x16f16(a1, hb, acc1, 0, 0, 0);
        }
        // ---- per-chunk epilogue: norm tree (lanes l^16, l^32) + bins
        float t = nd;
        t += __shfl_xor(t, 16, 64);
        t += __shfl_xor(t, 32, 64);
        const float idv = 1.0f / (sqrtf(t + 1e-7f) + 1e-7f);
        if (tok[ch] != 0) {        // masked doc: +1e7 -> dropped everywhere
#pragma unroll
            for (int r = 0; r < 4; ++r) {
                const int q0 = g4 * 4 + r;
                bin_one(acc0[r] * s_iq[q0] * idv, s_hist, q0);
                const int q1 = 16 + g4 * 4 + r;
                bin_one(acc1[r] * s_iq[q1] * idv, s_hist, q1);
            }
        }
    }
    __syncthreads();
    for (int i = tid; i < TQ * NFEAT; i += THREADS) {
        unsigned v = s_hist[i];
        if (v) atomicAdd(&ghist[b * TQ * NFEAT + i], v);
    }
}

// ---------------- finish: log + MLP + gate softmax ----------------
__global__ void k_finish(const unsigned* __restrict__ ghist,
                         const int* __restrict__ qsent, const float* __restrict__ idf,
                         const float* __restrict__ w1, const float* __restrict__ b1,
                         const float* __restrict__ w2, const float* __restrict__ b2,
                         const float* __restrict__ gw, const float* __restrict__ ow,
                         const float* __restrict__ ob, float* __restrict__ out) {
    int b = blockIdx.x;
    int lane = threadIdx.x;   // 64 threads, lanes 0..31 active
    float ffw = 0.f;
    float logit = -3.0e38f;
    if (lane < TQ) {
        const unsigned* h = ghist + (b * TQ + lane) * NFEAT;
        float f[NFEAT];
        for (int k = 0; k < NFEAT; ++k) f[k] = logf((float)h[k] + 1.0f);
        float s2 = b2[0];
        for (int n = 0; n < 5; ++n) {
            float s = b1[n];
            for (int k = 0; k < NFEAT; ++k) s = fmaf(f[k], w1[k * 5 + n], s);
            s2 = fmaf(tanhf(s), w2[n], s2);
        }
        ffw = tanhf(s2);
        int qt = qsent[b * TQ + lane];
        logit = idf[b * TQ + lane] * gw[0] + (qt == 0 ? -1e7f : 0.f);
    }
    float m = logit;
#pragma unroll
    for (int t = 1; t < 64; t <<= 1) m = fmaxf(m, __shfl_xor(m, t, 64));
    float e = expf(logit - m);            // inactive lanes -> exp(-inf) = 0
    float se = e, sw = e * ffw;
#pragma unroll
    for (int t = 1; t < 64; t <<= 1) {
        se += __shfl_xor(se, t, 64);
        sw += __shfl_xor(sw, t, 64);
    }
    if (lane == 0) out[b] = (sw / se) * ow[0] + ob[0];
}

extern "C" void kernel_launch(void* const* d_in, const int* in_sizes, int n_in,
                              void* d_out, int out_size, void* d_ws, size_t ws_size,
                              hipStream_t stream) {
    const int*   sent  = (const int*)d_in[0];
    const int*   qsent = (const int*)d_in[1];
    const float* idf   = (const float*)d_in[2];
    const float* emb   = (const float*)d_in[3];
    const float* w1    = (const float*)d_in[4];
    const float* b1    = (const float*)d_in[5];
    const float* w2    = (const float*)d_in[6];
    const float* b2    = (const float*)d_in[7];
    const float* gw    = (const float*)d_in[8];
    const float* ow    = (const float*)d_in[9];
    const float* ob    = (const float*)d_in[10];
    float* out = (float*)d_out;

    char* ws = (char*)d_ws;
    unsigned*  ghist  = (unsigned*)ws;                      // 240 KB
    _Float16*  qfrag  = (_Float16*)(ws + (256 << 10));      // 64 * 19456 B = 1.22 MB
    float*     invq   = (float*)(ws + (256 << 10) + (size_t)B_ * QF_BYTES);
    int*       sorted = (int*)(ws + (256 << 10) + (size_t)B_ * QF_BYTES
                               + (size_t)B_ * TQ * 4);      // 1 MB

    k_sort<<<B_, 256, 0, stream>>>(sent, sorted);
    k_qfrag<<<B_, 256, 0, stream>>>(qsent, emb, qfrag, invq, ghist);
    k_main<<<B_ * (TD / DPB), THREADS, 0, stream>>>(sorted, emb, qfrag, invq, ghist);
    k_finish<<<B_, 64, 0, stream>>>(ghist, qsent, idf, w1, b1, w2, b2, gw, ow, ob, out);
}